// Round 12
// baseline (1375.798 us; speedup 1.0000x reference)
//
#include <hip/hip_runtime.h>
#include <cstdint>
#include <cstddef>

// ---------------------------------------------------------------------------
// SpikingCoreFlow: bit-exact replication of the JAX reference on MI355X.
//
// Dims: B=128, D_in=1024, n_cores=64, N=256, A=256, n_out=10, cycles=32,
// pool_width = 17410.
//
// Pool "Pb" (bytes, rows of 128 = B): spikes rows [0,32768) = t*1024+d;
// buffer ping A [32768,49152), pong B [49152,65536); zeros 65536; ones 65537.
// Cycle t reads parity A if t even, writes the other.
//
// Exactness (verified R2-R11, absmax == 0.0):
//  - threefry2x32, jax_threefry_partitionable=True semantics.
//  - einsum = single ascending-a fused-FMA chain from 0 per (c,b,n); memb+=E
//    is one more rounded add. Mask operands are exactly {0.0f,1.0f}.
//
// Perf journal (core dispatch):
//  UNIFIED (R3-R11): (1) wave-shared operands through per-lane pipes pay 64x
//  (DS broadcast 20us, vector-load 27us). (2) blockIdx/readfirstlane-derived
//  uniform addresses DO scalarize to s_load (R11: VGPR=32 proves it). (3) A
//  rolled loop with dependent s_load->vmem->FMA per iter serializes at full
//  latency (R10 ~30us, R11 57us): prefetch must be EXPLICIT named-dbuf.
//  R12 = R10's M float table (masks built in-flight by epilogue inverse-
//  scatter + spike fillers + const prefill; verified) + per-lane weight
//  dwordx2 + scalar mask s_load_dwordx8 with 2-deep named double-buffer +
//  v_fmac_f32(acc, s_mask, v_w) (one legal scalar src; no VGPR build).
//  R8 lesson kept: graph = kernels only (init_kernel, no hipMemsetAsync).
// ---------------------------------------------------------------------------

#define N_CORES   64
#define NN        256
#define AA        256
#define BB        128
#define DIN       1024
#define NOUT      10
#define CYCLES    32
#define ROW_SPK   0u
#define ROW_A     32768u
#define ROW_B     49152u
#define ROW_ZERO  65536u
#define ROW_ONE   65537u

typedef float v2f __attribute__((ext_vector_type(2)));
typedef float f8v __attribute__((ext_vector_type(8)));

__device__ __forceinline__ void tf_round(uint32_t& x0, uint32_t& x1, int r) {
    x0 += x1;
    x1 = (x1 << r) | (x1 >> (32 - r));
    x1 ^= x0;
}

__device__ __forceinline__ void threefry2x32(uint32_t k0, uint32_t k1,
                                             uint32_t c0, uint32_t c1,
                                             uint32_t& o0, uint32_t& o1) {
    uint32_t ks2 = k0 ^ k1 ^ 0x1BD11BDAu;
    uint32_t x0 = c0 + k0, x1 = c1 + k1;
    tf_round(x0,x1,13); tf_round(x0,x1,15); tf_round(x0,x1,26); tf_round(x0,x1,6);
    x0 += k1; x1 += ks2 + 1u;
    tf_round(x0,x1,17); tf_round(x0,x1,29); tf_round(x0,x1,16); tf_round(x0,x1,24);
    x0 += ks2; x1 += k0 + 2u;
    tf_round(x0,x1,13); tf_round(x0,x1,15); tf_round(x0,x1,26); tf_round(x0,x1,6);
    x0 += k0; x1 += k1 + 3u;
    tf_round(x0,x1,17); tf_round(x0,x1,29); tf_round(x0,x1,16); tf_round(x0,x1,24);
    x0 += k1; x1 += ks2 + 4u;
    tf_round(x0,x1,13); tf_round(x0,x1,15); tf_round(x0,x1,26); tf_round(x0,x1,6);
    x0 += ks2; x1 += k0 + 5u;
    o0 = x0; o1 = x1;
}

// All launch-time state init in ONE kernel (graph stays kernels-only).
__global__ void init_kernel(unsigned char* __restrict__ Pb,
                            float* __restrict__ memb,
                            float* __restrict__ M0,
                            uint32_t* __restrict__ inv_cnt,
                            uint32_t* __restrict__ spike_cnt,
                            float* __restrict__ out) {
    int idx = blockIdx.x * 256 + threadIdx.x;       // 2048 blocks -> 524288
    float4 z = {0.0f, 0.0f, 0.0f, 0.0f};
    *(float4*)(memb + (size_t)idx * 4) = z;                         // 8 MiB
    *(float4*)(M0   + (size_t)idx * 4) = z;                         // 8 MiB
    *(uint32_t*)(Pb + (size_t)ROW_A * 128 + (size_t)idx * 4) = 0u;  // 2 MiB
    if (idx < 32)
        *(uint32_t*)(Pb + (size_t)ROW_ZERO * 128 + idx * 4) = 0u;
    else if (idx < 64)
        *(uint32_t*)(Pb + (size_t)ROW_ONE * 128 + (idx - 32) * 4) = 0x01010101u;
    if (idx < BB * NOUT) out[idx] = 0.0f;
    if (idx < 16384) inv_cnt[idx] = 0u;
    if (idx == 16384) *spike_cnt = 0u;
}

__global__ void spikes_kernel(const float* __restrict__ x,
                              unsigned char* __restrict__ Pb) {
    __shared__ unsigned char S[32 * 132];
    int bx  = blockIdx.x;        // 1024 = 32 t * 32 dblk
    int t   = bx >> 5;
    int d0  = (bx & 31) * 32;
    int tid = threadIdx.x;

    uint32_t k0, k1;
    threefry2x32(0u, 42u, 0u, (uint32_t)t, k0, k1);   // keys[t] = (w0, w1)

    #pragma unroll
    for (int k = 0; k < 16; ++k) {
        int e  = tid + k * 256;      // 0..4095 = 128 bb * 32 dl
        int bb = e >> 5;
        int dl = e & 31;
        int d  = d0 + dl;
        uint32_t f = (uint32_t)(bb * 1024 + d);
        uint32_t y0, y1;
        threefry2x32(k0, k1, 0u, f, y0, y1);
        uint32_t bits = y0 ^ y1;                      // xor-fold
        float u = __uint_as_float((bits >> 9) | 0x3f800000u) - 1.0f;
        S[dl * 132 + bb] = (u < x[bb * 1024 + d]) ? 1 : 0;
    }
    __syncthreads();

    int dl = tid >> 3;
    int bg = tid & 7;
    const uint32_t* Srow = (const uint32_t*)(S + dl * 132);
    uint4 v;
    v.x = Srow[bg * 4 + 0]; v.y = Srow[bg * 4 + 1];
    v.z = Srow[bg * 4 + 2]; v.w = Srow[bg * 4 + 3];
    size_t row = (size_t)t * 1024 + d0 + dl;
    *(uint4*)(Pb + row * 128 + bg * 16) = v;
}

// WT[c][a][n] = W[c][n][a]
__global__ void wt_kernel(const float* __restrict__ W, float* __restrict__ WT) {
    __shared__ float T[32][33];
    int bx = blockIdx.x;            // 4096 = 64 c * 8 tn * 8 ta
    int c  = bx >> 6;
    int tn = (bx >> 3) & 7;
    int ta = bx & 7;
    int tid = threadIdx.x;
    int r  = tid >> 3;
    int q4 = (tid & 7) * 4;

    const float* src = W + (size_t)c * 65536 + (size_t)(tn * 32 + r) * 256 + ta * 32 + q4;
    float4 v = *(const float4*)src;
    T[r][q4 + 0] = v.x; T[r][q4 + 1] = v.y; T[r][q4 + 2] = v.z; T[r][q4 + 3] = v.w;
    __syncthreads();

    float4 o;
    o.x = T[q4 + 0][r]; o.y = T[q4 + 1][r]; o.z = T[q4 + 2][r]; o.w = T[q4 + 3][r];
    float* dst = WT + (size_t)c * 65536 + (size_t)(ta * 32 + r) * 256 + tn * 32 + q4;
    *(float4*)dst = o;
}

// out_off[t][o] = byte offset of pool2 row for out_src at cycle t (WRITE parity)
__global__ void outoff_kernel(const int* __restrict__ outsrc,
                              uint32_t* __restrict__ out_off) {
    int tid = threadIdx.x;
    for (int idx = tid; idx < CYCLES * NOUT; idx += 256) {
        int t = idx / NOUT, o = idx % NOUT;
        int j = outsrc[o];
        uint32_t row;
        if (j < 1024)        row = (uint32_t)(t * 1024 + j);
        else if (j < 17408)  row = (((t & 1) == 0) ? ROW_B : ROW_A) + (uint32_t)(j - 1024);
        else                 row = (j == 17408) ? ROW_ZERO : ROW_ONE;
        out_off[idx] = row * 128u;
    }
}

// Once per launch (after spikes): classify axons.
__global__ void setup_kernel(const int* __restrict__ axon,
                             const unsigned char* __restrict__ Pb,
                             float* __restrict__ M0,
                             float* __restrict__ M1,
                             uint32_t* __restrict__ inv,
                             uint32_t* __restrict__ inv_cnt,
                             uint32_t* __restrict__ spike_list,
                             uint32_t* __restrict__ spike_cnt) {
    int ca = blockIdx.x * 256 + threadIdx.x;        // 64 blocks -> 16384
    int j  = axon[ca];
    if (j < 1024) {
        uint32_t pos = atomicAdd(spike_cnt, 1u);
        spike_list[pos] = (uint32_t)ca | ((uint32_t)j << 14);
        const unsigned char* src = Pb + (size_t)j * 128;    // t=0 spike row
        float* dst = M0 + (size_t)ca * 128;
        #pragma unroll
        for (int q = 0; q < 8; ++q) {
            uint4 v = *(const uint4*)(src + q * 16);
            const unsigned char* pb = (const unsigned char*)&v;
            #pragma unroll
            for (int h = 0; h < 4; ++h) {
                float4 f;
                f.x = (float)pb[4*h+0]; f.y = (float)pb[4*h+1];
                f.z = (float)pb[4*h+2]; f.w = (float)pb[4*h+3];
                *(float4*)(dst + q * 16 + 4 * h) = f;
            }
        }
    } else if (j < 17408) {
        int row = j - 1024;                       // = c_src*256 + n
        uint32_t pos = atomicAdd(&inv_cnt[row], 1u);
        if (pos < 16) inv[row * 16 + pos] = (uint32_t)ca;
    } else if (j == 17409) {
        float* d0 = M0 + (size_t)ca * 128;
        float* d1 = M1 + (size_t)ca * 128;
        float4 one = {1.0f, 1.0f, 1.0f, 1.0f};
        #pragma unroll
        for (int q = 0; q < 32; ++q) { *(float4*)(d0 + q*4) = one; *(float4*)(d1 + q*4) = one; }
    } else {  // 17408: zeros -> M1 0.0 (M0 zeroed by init)
        float* d1 = M1 + (size_t)ca * 128;
        float4 z = {0.0f, 0.0f, 0.0f, 0.0f};
        #pragma unroll
        for (int q = 0; q < 32; ++q) *(float4*)(d1 + q*4) = z;
    }
}

// One cycle. 544 blocks x 256 thr: [0,512) main = (c, bgq), [512,544) spike
// fillers for M_next. Main wave: nh = wid&1, bg = bgq*2 + (wid>>1); lane owns
// n-pair (n = nh*128 + 2*lane + {0,1}), 8 b's (bg*8..).
// Hot loop, 4-a chunks, 2-deep named dbuf:
//   masks: uniform s_load_dwordx8 x4 (readfirstlane'd base -> SGPRs)
//   weights: per-lane global dwordx2 x4 (vmcnt pipeline)
//   FMA: 64x v_fmac_f32(acc, s_mask, v_w) -- one scalar src, no VGPR build.
// Epilogue: memb RMW + fired bytes -> Pb + inverse-scatter floats -> M_next.
__global__ __launch_bounds__(256, 2) void core_kernel(
    const unsigned char* __restrict__ Pb,
    unsigned char* __restrict__ Pw,
    const float* __restrict__ WT,
    const float* __restrict__ M_cur,
    float* __restrict__ M_next,
    float* __restrict__ memb,
    const float* __restrict__ thresholds,
    const uint32_t* __restrict__ inv,
    const uint32_t* __restrict__ inv_cnt,
    const uint32_t* __restrict__ spike_list,
    const uint32_t* __restrict__ spike_cnt,
    uint32_t wbyte_base,
    const uint32_t* __restrict__ out_off_prev,
    float* __restrict__ d_out,
    int do_out,
    int t_next)
{
    int tid = threadIdx.x;
    int bx  = blockIdx.x;

    if (bx >= 512) {                      // ---- spike-axon filler blocks ----
        if (t_next > 0) {
            int nsp = (int)*spike_cnt;
            int ntask = nsp * 8;
            for (int task = (bx - 512) * 256 + tid; task < ntask; task += 32 * 256) {
                int e  = task >> 3;
                int ch = task & 7;
                uint32_t sl = spike_list[e];
                int ca = (int)(sl & 16383u);
                int j  = (int)(sl >> 14);
                const unsigned char* src = Pb + ((size_t)t_next * 1024 + j) * 128 + ch * 16;
                uint4 v = *(const uint4*)src;
                const unsigned char* pb = (const unsigned char*)&v;
                float* dst = M_next + (size_t)ca * 128 + ch * 16;
                #pragma unroll
                for (int q = 0; q < 4; ++q) {
                    float4 f;
                    f.x = (float)pb[4*q+0]; f.y = (float)pb[4*q+1];
                    f.z = (float)pb[4*q+2]; f.w = (float)pb[4*q+3];
                    *(float4*)(dst + 4*q) = f;
                }
            }
        }
        return;
    }

    // fused out-update for the PREVIOUS cycle (reads current READ parity)
    if (do_out && bx == 0 && tid < BB) {
        #pragma unroll
        for (int o = 0; o < NOUT; ++o) {
            uint32_t off = out_off_prev[o];
            d_out[tid * NOUT + o] += (float)Pb[off + (uint32_t)tid];
        }
    }

    // decode: 512 = 8 xcd * 8 c-local * 8 bgq  (c grouped per XCD for L2)
    int c    = (bx & 7) * 8 + ((bx >> 3) & 7);
    int bgq  = bx >> 6;                 // 0..7
    int lane = tid & 63;
    int wid  = __builtin_amdgcn_readfirstlane(tid >> 6);
    int nh   = wid & 1;
    int bg   = bgq * 2 + (wid >> 1);    // 0..15
    int n0   = nh * 128;

    // wave-uniform mask base (floats): M_cur + c*32768 + bg*8
    int mbase = __builtin_amdgcn_readfirstlane(c * 32768 + bg * 8);
    const float* Mrow = M_cur + mbase;                   // + a*128 per a
    const float* wtp  = WT + (size_t)c * 65536 + n0 + lane * 2;

    float acc0[8], acc1[8];
    #pragma unroll
    for (int b = 0; b < 8; ++b) { acc0[b] = 0.0f; acc1[b] = 0.0f; }

    f8v mA[4], mB[4];      // scalar mask buffers (32 SGPRs each)
    v2f wA[4], wB[4];      // per-lane weight buffers

#define LOADM(Mb, ch)                                                         \
    { _Pragma("unroll")                                                       \
      for (int i_ = 0; i_ < 4; ++i_)                                          \
          Mb[i_] = *(const f8v*)(Mrow + (size_t)((ch) * 4 + i_) * 128); }

#define LOADW(Wb, ch)                                                         \
    { _Pragma("unroll")                                                       \
      for (int i_ = 0; i_ < 4; ++i_)                                          \
          Wb[i_] = *(const v2f*)(wtp + (size_t)((ch) * 4 + i_) * 256); }

#define FMACH(Mb, Wb)                                                         \
    { _Pragma("unroll")                                                       \
      for (int i_ = 0; i_ < 4; ++i_) {                                        \
          float w0_ = Wb[i_].x, w1_ = Wb[i_].y;                               \
          _Pragma("unroll")                                                   \
          for (int b_ = 0; b_ < 8; ++b_) {                                    \
              acc0[b_] = fmaf(w0_, Mb[i_][b_], acc0[b_]);                     \
              acc1[b_] = fmaf(w1_, Mb[i_][b_], acc1[b_]);                     \
          }                                                                   \
      } }

    LOADM(mA, 0); LOADW(wA, 0);
    for (int ch = 0; ch < 64; ch += 2) {
        LOADM(mB, ch + 1); LOADW(wB, ch + 1);
        FMACH(mA, wA);
        if (ch + 2 < 64) { LOADM(mA, ch + 2); LOADW(wA, ch + 2); }
        FMACH(mB, wB);
    }
#undef LOADM
#undef LOADW
#undef FMACH

    // ---- Epilogue: memb RMW + fired bytes + M_next inverse-scatter ----
    float thr = thresholds[c];

#define EPI(NJ, ACC)                                                          \
    { int n   = n0 + lane * 2 + NJ;                                           \
      int row = c * 256 + n;                                                  \
      size_t mi = (size_t)row * 128 + bg * 8;                                 \
      float4 p0 = *(const float4*)(memb + mi);                                \
      float4 p1 = *(const float4*)(memb + mi + 4);                            \
      float vv[8];                                                            \
      vv[0] = p0.x + ACC[0]; vv[1] = p0.y + ACC[1];                           \
      vv[2] = p0.z + ACC[2]; vv[3] = p0.w + ACC[3];                           \
      vv[4] = p1.x + ACC[4]; vv[5] = p1.y + ACC[5];                           \
      vv[6] = p1.z + ACC[6]; vv[7] = p1.w + ACC[7];                           \
      uint32_t flo = 0, fhi = 0;                                              \
      float st[8], ff[8];                                                     \
      _Pragma("unroll")                                                       \
      for (int k = 0; k < 8; ++k) {                                           \
          bool f = vv[k] > thr;                                               \
          st[k] = f ? 0.0f : vv[k];                                           \
          ff[k] = f ? 1.0f : 0.0f;                                            \
          if (k < 4) flo |= (f ? 1u : 0u) << (8 * k);                         \
          else       fhi |= (f ? 1u : 0u) << (8 * (k - 4));                   \
      }                                                                       \
      float4 s0 = {st[0], st[1], st[2], st[3]};                               \
      float4 s1 = {st[4], st[5], st[6], st[7]};                               \
      *(float4*)(memb + mi)     = s0;                                         \
      *(float4*)(memb + mi + 4) = s1;                                         \
      uint2 fb = {flo, fhi};                                                  \
      *(uint2*)(Pw + wbyte_base + mi) = fb;                                   \
      int cnt = (int)inv_cnt[row];                                            \
      float4 q0 = {ff[0], ff[1], ff[2], ff[3]};                               \
      float4 q1 = {ff[4], ff[5], ff[6], ff[7]};                               \
      for (int k = 0; k < cnt; ++k) {                                         \
          int ca = (int)inv[row * 16 + k];                                    \
          float* dst = M_next + (size_t)ca * 128 + bg * 8;                    \
          *(float4*)dst       = q0;                                           \
          *(float4*)(dst + 4) = q1;                                           \
      } }

    EPI(0, acc0)
    EPI(1, acc1)
#undef EPI
}

__global__ void tail_kernel(const unsigned char* __restrict__ Pb,
                            const uint32_t* __restrict__ out_off31,
                            float* __restrict__ d_out) {
    int tid = threadIdx.x;
    if (tid < BB) {
        #pragma unroll
        for (int o = 0; o < NOUT; ++o) {
            uint32_t off = out_off31[o];
            d_out[tid * NOUT + o] += (float)Pb[off + (uint32_t)tid];
        }
    }
}

extern "C" void kernel_launch(void* const* d_in, const int* in_sizes, int n_in,
                              void* d_out_, int out_size, void* d_ws, size_t ws_size,
                              hipStream_t stream) {
    const float* x          = (const float*)d_in[0];
    const float* W          = (const float*)d_in[1];
    const float* thresholds = (const float*)d_in[2];
    const int*   axon       = (const int*)d_in[3];
    const int*   outsrc     = (const int*)d_in[4];
    // d_in[5] = cycles; fixed instance -> 32.

    if (ws_size < (size_t)80 * 1024 * 1024) return;

    unsigned char* ws         = (unsigned char*)d_ws;
    unsigned char* Pb         = ws;                                     // 8.4 MB
    float*         WT         = (float*)(ws + (size_t)(16u << 20));     // 16 MiB
    uint32_t*      out_off    = (uint32_t*)(ws + (size_t)(34u << 20));
    float*         memb       = (float*)(ws + (size_t)(36u << 20));     // 8 MiB
    float*         M0         = (float*)(ws + (size_t)(48u << 20));     // 8 MiB
    float*         M1         = (float*)(ws + (size_t)(56u << 20));     // 8 MiB
    uint32_t*      inv        = (uint32_t*)(ws + (size_t)(64u << 20));  // 1 MiB
    uint32_t*      inv_cnt    = (uint32_t*)(ws + (size_t)(66u << 20));  // 64 KiB
    uint32_t*      spike_list = (uint32_t*)(ws + (size_t)(67u << 20));  // 64 KiB
    uint32_t*      spike_cnt  = (uint32_t*)(ws + (size_t)(68u << 20));
    float*         out        = (float*)d_out_;

    init_kernel<<<2048, 256, 0, stream>>>(Pb, memb, M0, inv_cnt, spike_cnt, out);
    spikes_kernel<<<1024, 256, 0, stream>>>(x, Pb);
    wt_kernel<<<4096, 256, 0, stream>>>(W, WT);
    outoff_kernel<<<1, 256, 0, stream>>>(outsrc, out_off);
    setup_kernel<<<64, 256, 0, stream>>>(axon, Pb, M0, M1, inv, inv_cnt,
                                         spike_list, spike_cnt);

    float* Mbuf[2] = {M0, M1};
    for (int t = 0; t < CYCLES; ++t) {
        uint32_t wrow = ((t & 1) == 0) ? ROW_B : ROW_A;   // write parity
        const uint32_t* oprev = out_off + (t > 0 ? (t - 1) * NOUT : 0);
        core_kernel<<<544, 256, 0, stream>>>(
            Pb, Pb, WT, Mbuf[t & 1], Mbuf[(t + 1) & 1], memb, thresholds,
            inv, inv_cnt, spike_list, spike_cnt,
            wrow * 128u, oprev, out, t > 0 ? 1 : 0,
            (t < CYCLES - 1) ? (t + 1) : 0);
    }
    tail_kernel<<<1, 128, 0, stream>>>(Pb, out_off + 31 * NOUT, out);
}